// Round 8
// baseline (6581.938 us; speedup 1.0000x reference)
//
#include <hip/hip_runtime.h>
#include <hip/hip_fp16.h>

#define NT    365
#define NGRID 1000
#define NXI   20
#define HID   256
#define GATES 1024
#define MROWS 365000          // NT*NGRID
#define MBLK  5704            // ceil(MROWS/64)
#define MPAD  (MBLK * 64)
#define NCL   63              // clusters (16 pts each, last ragged)
#define CPTS  16
#define HX_TOT ((size_t)NT * NCL * 1024)   // u64 slots, deep buffer (188MB)
#define HX_ZERO ((size_t)NCL * 1024)       // t=0 region: zeros (h_0 = 0)

typedef _Float16 half8 __attribute__((ext_vector_type(8)));
typedef float floatx4 __attribute__((ext_vector_type(4)));
typedef unsigned long long u64;

#define SENT 0xFFFFFFFFFFFFFFFFull   // 4x fp16 -NaN: unreachable (|h|<=1)

// Module-scope globals (d_ws too small). Fully rewritten/reset every launch.
__device__ _Float16 g_gx[(size_t)MPAD * GATES];   // gx, block-local column layout
__device__ _Float16 g_wif[64 * 8 * 512];          // W_ih B-frags (global n-tiles)
__device__ _Float16 g_whf[2 * 32 * 8 * 64 * 8];   // W_hh B-frags, split by rec block
// h exchange, A-FRAGMENT ORDER, plane-split: slot[c][ks][lane] (c = u64 half
// of the half8). Poll loads are lane-contiguous -> perfectly coalesced
// (round 7's regression was 512B-strided polls = 64 LLC transactions/load).
// Sentinel protocol: value is its own ready-flag; deep t-indexed buffer.
__device__ u64 g_hx[HX_TOT];

__device__ __forceinline__ float fsig(float x) {
  return __fdividef(1.f, 1.f + __expf(-x));
}
__device__ __forceinline__ float ftanh(float x) {
  return 1.f - __fdividef(2.f, __expf(2.f * x) + 1.f);
}

// ---- init: zero y, zero g_hx[t=0], sentinel-fill the rest -----------------
__global__ __launch_bounds__(256) void init_kernel(float* __restrict__ y) {
  const size_t i = (size_t)blockIdx.x * 256 + threadIdx.x;
  const size_t j = i * 2;
  if (j < HX_TOT)     g_hx[j]     = (j < HX_ZERO)     ? 0ull : SENT;
  if (j + 1 < HX_TOT) g_hx[j + 1] = (j + 1 < HX_ZERO) ? 0ull : SENT;
  if (i < MROWS) y[i] = 0.f;
}

// ---- pack weights into MFMA B-fragment layouts ----------------------------
// B-frag 16x16x32: lane holds B[n=tile*16+(lane&15)][k=ks*32+(lane>>4)*8+j]
__global__ __launch_bounds__(256) void pack_wf_kernel(
    const float* __restrict__ W_ih, const float* __restrict__ W_hh) {
  const int gid = blockIdx.x * 256 + threadIdx.x;   // 0..65535
  const float* src;
  _Float16* dst;
  int n, k0, lane;
  if (gid < 32768) {                 // W_ih -> g_wif, global n-tile layout
    const int tile = gid >> 9;
    const int ks   = (gid >> 6) & 7;
    lane = gid & 63;
    n  = tile * 16 + (lane & 15);
    k0 = ks * 32 + (lane >> 4) * 8;
    src = W_ih + n * HID + k0;
    dst = g_wif + ((size_t)(tile * 8 + ks) * 64 + lane) * 8;
  } else {                           // W_hh -> g_whf, [b][ltile][ks] layout
    const int rem = gid - 32768;
    const int b2  = rem >> 14;       // owning rec block (dim half)
    const int lt  = (rem >> 9) & 31; // local tile = tau*8 + sub
    const int ks  = (rem >> 6) & 7;
    lane = rem & 63;
    const int nt = (lt >> 3) * 16 + b2 * 8 + (lt & 7);
    n  = nt * 16 + (lane & 15);
    k0 = ks * 32 + (lane >> 4) * 8;
    src = W_hh + n * HID + k0;
    dst = g_whf + ((size_t)((b2 * 32 + lt) * 8 + ks) * 64 + lane) * 8;
  }
  const float4 a = *(const float4*)(src);
  const float4 b = *(const float4*)(src + 4);
  half8 h;
  h[0] = (_Float16)a.x; h[1] = (_Float16)a.y; h[2] = (_Float16)a.z; h[3] = (_Float16)a.w;
  h[4] = (_Float16)b.x; h[5] = (_Float16)b.y; h[6] = (_Float16)b.z; h[7] = (_Float16)b.w;
  *(half8*)dst = h;
}

// ---- gx = relu(x@W_in.T+b_in) @ W_ih.T + (b_ih+b_hh), fused ---------------
// Output column layout per row: phi(g) = b*512 + tau*128 + (g&127).
__global__ __launch_bounds__(256, 2) void gx_kernel(
    const float* __restrict__ x, const float* __restrict__ W_in,
    const float* __restrict__ b_in, const float* __restrict__ b_ih,
    const float* __restrict__ b_hh) {
  __shared__ float s_x[64 * NXI];
  __shared__ _Float16 s_x0[64 * 264];
  __shared__ _Float16 s_out[64 * 264];

  const int tid  = threadIdx.x;
  const int lane = tid & 63;
  const int w    = tid >> 6;
  const int m0   = blockIdx.x * 64;

  #pragma unroll
  for (int i = 0; i < 5; ++i) {
    const int idx = i * 256 + tid;
    size_t g = (size_t)m0 * NXI + idx;
    const size_t gmax = (size_t)MROWS * NXI - 1;
    if (g > gmax) g = gmax;
    s_x[idx] = x[g];
  }
  float wv[NXI];
  #pragma unroll
  for (int k = 0; k < NXI; ++k) wv[k] = W_in[tid * NXI + k];
  const float bv = b_in[tid];
  __syncthreads();

  for (int r = 0; r < 64; ++r) {
    float acc = bv;
    #pragma unroll
    for (int qq = 0; qq < 5; ++qq) {
      const float4 xa = *(const float4*)&s_x[r * NXI + qq * 4];
      acc += xa.x * wv[qq * 4 + 0] + xa.y * wv[qq * 4 + 1] +
             xa.z * wv[qq * 4 + 2] + xa.w * wv[qq * 4 + 3];
    }
    s_x0[r * 264 + tid] = (_Float16)fmaxf(acc, 0.f);
  }
  __syncthreads();

  for (int ng = 0; ng < 4; ++ng) {    // 4 groups of 256 gates
    floatx4 acc[4][4];
    #pragma unroll
    for (int mi = 0; mi < 4; ++mi)
      #pragma unroll
      for (int ni = 0; ni < 4; ++ni) acc[mi][ni] = (floatx4){0.f, 0.f, 0.f, 0.f};

    #pragma unroll
    for (int ks = 0; ks < 8; ++ks) {
      half8 a[4], bfr[4];
      #pragma unroll
      for (int mi = 0; mi < 4; ++mi)
        a[mi] = *(const half8*)&s_x0[(mi * 16 + (lane & 15)) * 264 + ks * 32 + (lane >> 4) * 8];
      #pragma unroll
      for (int ni = 0; ni < 4; ++ni) {
        const int nt = ng * 16 + w * 4 + ni;
        bfr[ni] = *(const half8*)(g_wif + ((size_t)(nt * 8 + ks) * 64 + lane) * 8);
      }
      #pragma unroll
      for (int mi = 0; mi < 4; ++mi)
        #pragma unroll
        for (int ni = 0; ni < 4; ++ni)
          acc[mi][ni] = __builtin_amdgcn_mfma_f32_16x16x32_f16(a[mi], bfr[ni], acc[mi][ni], 0, 0, 0);
    }

    #pragma unroll
    for (int ni = 0; ni < 4; ++ni) {
      const int g = ng * 256 + (w * 4 + ni) * 16 + (lane & 15);
      const float bias = b_ih[g] + b_hh[g];
      const int colw = (w * 4 + ni) * 16 + (lane & 15);
      #pragma unroll
      for (int mi = 0; mi < 4; ++mi)
        #pragma unroll
        for (int r = 0; r < 4; ++r)
          s_out[(mi * 16 + (lane >> 4) * 4 + r) * 264 + colw] = (_Float16)(acc[mi][ni][r] + bias);
    }
    __syncthreads();

    #pragma unroll
    for (int i = 0; i < 8; ++i) {
      const int cid = i * 256 + tid;             // 2048 chunks of 8 halfs
      const int row = cid >> 5;
      const int c8  = (cid & 31) * 8;
      const half8 v = *(const half8*)&s_out[row * 264 + c8];
      const int phi = ((c8 >> 7) & 1) * 512 + ng * 128 + (c8 & 127);
      *(half8*)(g_gx + (size_t)(m0 + row) * GATES + phi) = v;
    }
    __syncthreads();
  }
}

// ---- recurrent: 63 clusters x 2 blocks; 256KB W_hh/block in registers ----
// Block b owns h dims [b*128,(b+1)*128) = ks slices b*4..b*4+3. Own half
// comes from LDS (s_hl, written at cell-update in A-order); only the PEER's
// 4 ks slices are polled from the LLC (coalesced, plane-split A-order).
// Own-half MFMAs run while peer data is in flight.
__global__ __launch_bounds__(256, 1) void rec_kernel(
    const float* __restrict__ W_out, const float* __restrict__ b_out,
    float* __restrict__ y) {
  __shared__ float    s_g[16 * 516];   // 16 pts x 512 local gates (+4 pad)
  __shared__ _Float16 s_gx[16 * 512];
  __shared__ u64      s_hl[512];       // own half, A-order: c*256 + ks_rel*64 + lane

  const int tid  = threadIdx.x;
  const int lane = tid & 63;
  const int w    = tid >> 6;
  const int c    = blockIdx.x >> 1;    // cluster
  const int b    = blockIdx.x & 1;     // dim-half owner

  // one-time: 256KB W_hh slice -> registers (wave w: local tiles w*8..w*8+8)
  half8 wf[8][8];
  #pragma unroll
  for (int i = 0; i < 8; ++i)
    #pragma unroll
    for (int ks = 0; ks < 8; ++ks)
      wf[i][ks] = *(const half8*)(g_whf + ((size_t)((b * 32 + w * 8 + i) * 8 + ks) * 64 + lane) * 8);

  // cell ownership: pt = tid>>4, local dims q*8..q*8+8 (global b*128 + ...)
  const int pt = tid >> 4;
  const int q  = tid & 15;
  float cs[8];
  float wo[8];
  #pragma unroll
  for (int j = 0; j < 8; ++j) {
    cs[j] = 0.f;
    wo[j] = W_out[b * 128 + q * 8 + j];
  }
  const float bo = (b == 0) ? b_out[0] : 0.f;
  const int n_pt  = c * CPTS + pt;
  const int rn_pt = (n_pt < NGRID) ? n_pt : (NGRID - 1);

  const int ks_own0  = b * 4;          // our ks slices
  const int ks_peer0 = 4 - b * 4;      // peer's ks slices
  // publish/LDS index pieces: kb = b*16+q -> ks = b*4+(q>>2), lane_a = pt+16*(q&3)
  const int pub_lane = pt + 16 * (q & 3);
  const int pub_ks_rel = q >> 2;

  // h_0 = 0 in own-half LDS
  for (int i = tid; i < 512; i += 256) s_hl[i] = 0ull;
  __syncthreads();

  for (int t = 0; t < NT; ++t) {
    // 1) gx prefetch (HBM, hidden behind everything): 64B per thread
    half8 gxr[4];
    {
      const _Float16* gsrc = g_gx + ((size_t)t * NGRID + rn_pt) * GATES + b * 512 + q * 32;
      #pragma unroll
      for (int k = 0; k < 4; ++k) gxr[k] = *(const half8*)(gsrc + k * 8);
    }

    // 2) issue peer-half poll loads (coalesced: addr stride 8B across lanes)
    const u64* hsrc = g_hx + ((size_t)t * NCL + c) * 1024;
    u64 pv[8];
    #pragma unroll
    for (int kk = 0; kk < 4; ++kk) {
      pv[2 * kk]     = __hip_atomic_load(hsrc +       (ks_peer0 + kk) * 64 + lane,
                                         __ATOMIC_RELAXED, __HIP_MEMORY_SCOPE_AGENT);
      pv[2 * kk + 1] = __hip_atomic_load(hsrc + 512 + (ks_peer0 + kk) * 64 + lane,
                                         __ATOMIC_RELAXED, __HIP_MEMORY_SCOPE_AGENT);
    }

    floatx4 acc[8];
    #pragma unroll
    for (int i = 0; i < 8; ++i) acc[i] = (floatx4){0.f, 0.f, 0.f, 0.f};

    // 3) own-half MFMAs from LDS while peer loads are in flight
    #pragma unroll
    for (int kk = 0; kk < 4; ++kk) {
      union { u64 u[2]; half8 h; } af;
      af.u[0] = s_hl[kk * 64 + lane];
      af.u[1] = s_hl[256 + kk * 64 + lane];
      #pragma unroll
      for (int i = 0; i < 8; ++i)
        acc[i] = __builtin_amdgcn_mfma_f32_16x16x32_f16(af.h, wf[i][ks_own0 + kk], acc[i], 0, 0, 0);
    }

    // 4) peer-half: spin per slice (value is its own flag), then MFMA
    #pragma unroll
    for (int kk = 0; kk < 4; ++kk) {
      const u64* a0 = hsrc +       (ks_peer0 + kk) * 64 + lane;
      const u64* a1 = hsrc + 512 + (ks_peer0 + kk) * 64 + lane;
      int tries = 0;
      while (pv[2 * kk] == SENT && ++tries < (1 << 20))
        pv[2 * kk] = __hip_atomic_load(a0, __ATOMIC_RELAXED, __HIP_MEMORY_SCOPE_AGENT);
      tries = 0;
      while (pv[2 * kk + 1] == SENT && ++tries < (1 << 20))
        pv[2 * kk + 1] = __hip_atomic_load(a1, __ATOMIC_RELAXED, __HIP_MEMORY_SCOPE_AGENT);
      union { u64 u[2]; half8 h; } af;
      af.u[0] = pv[2 * kk];
      af.u[1] = pv[2 * kk + 1];
      #pragma unroll
      for (int i = 0; i < 8; ++i)
        acc[i] = __builtin_amdgcn_mfma_f32_16x16x32_f16(af.h, wf[i][ks_peer0 + kk], acc[i], 0, 0, 0);
    }

    // 5) stage gate pre-acts + gx to LDS
    #pragma unroll
    for (int i = 0; i < 8; ++i) {
      const int col = (w * 8 + i) * 16 + (lane & 15);
      #pragma unroll
      for (int r = 0; r < 4; ++r)
        s_g[((lane >> 4) * 4 + r) * 516 + col] = acc[i][r];
    }
    {
      _Float16* d = &s_gx[pt * 512 + q * 32];
      #pragma unroll
      for (int k = 0; k < 4; ++k) *(half8*)(d + k * 8) = gxr[k];
    }
    __syncthreads(); // B1: s_g, s_gx ready; s_hl fully consumed

    // 6) cell update (8 dims); publish peer copy + own-half LDS ASAP
    {
      const float*    gp = &s_g[pt * 516 + q * 8];
      const _Float16* xp = &s_gx[pt * 512 + q * 8];
      union { u64 u[2]; _Float16 h[8]; } pub;
      float yp = 0.f;
      #pragma unroll
      for (int j = 0; j < 8; ++j) {
        const float gi = gp[j]       + (float)xp[j];
        const float gf = gp[128 + j] + (float)xp[128 + j];
        const float gg = gp[256 + j] + (float)xp[256 + j];
        const float go = gp[384 + j] + (float)xp[384 + j];
        const float i_ = fsig(gi);
        const float f_ = fsig(gf);
        const float g_ = ftanh(gg);
        const float o_ = fsig(go);
        cs[j] = f_ * cs[j] + i_ * g_;
        const float h = o_ * ftanh(cs[j]);
        pub.h[j] = (_Float16)h;
        yp += wo[j] * h;
      }
      if (t < NT - 1) {
        u64* dst = g_hx + ((size_t)(t + 1) * NCL + c) * 1024
                 + (ks_own0 + pub_ks_rel) * 64 + pub_lane;
        __hip_atomic_store(dst,       pub.u[0], __ATOMIC_RELAXED, __HIP_MEMORY_SCOPE_AGENT);
        __hip_atomic_store(dst + 512, pub.u[1], __ATOMIC_RELAXED, __HIP_MEMORY_SCOPE_AGENT);
      }
      s_hl[pub_ks_rel * 64 + pub_lane]       = pub.u[0];
      s_hl[256 + pub_ks_rel * 64 + pub_lane] = pub.u[1];
      yp += __shfl_xor(yp, 1);
      yp += __shfl_xor(yp, 2);
      yp += __shfl_xor(yp, 4);
      yp += __shfl_xor(yp, 8);
      if (q == 0 && n_pt < NGRID)
        atomicAdd(&y[(size_t)t * NGRID + n_pt], yp + bo);
    }
    __syncthreads(); // B2: s_hl(t+1) ready; s_g/s_gx reusable; stores drained
  }
}

extern "C" void kernel_launch(void* const* d_in, const int* in_sizes, int n_in,
                              void* d_out, int out_size, void* d_ws, size_t ws_size,
                              hipStream_t stream) {
  (void)in_sizes; (void)n_in; (void)out_size; (void)d_ws; (void)ws_size;
  const float* x     = (const float*)d_in[0];
  // d_in[1] = wt_ih (zeros in eval mode, unused)
  const float* W_in  = (const float*)d_in[2];
  const float* b_in  = (const float*)d_in[3];
  const float* W_ih  = (const float*)d_in[4];
  const float* W_hh  = (const float*)d_in[5];
  const float* b_ih  = (const float*)d_in[6];
  const float* b_hh  = (const float*)d_in[7];
  const float* W_out = (const float*)d_in[8];
  const float* b_out = (const float*)d_in[9];
  float* y           = (float*)d_out;

  const int init_blocks = (int)((HX_TOT / 2 + 255) / 256);
  hipLaunchKernelGGL(init_kernel, dim3(init_blocks), dim3(256), 0, stream, y);
  hipLaunchKernelGGL(pack_wf_kernel, dim3(256), dim3(256), 0, stream, W_ih, W_hh);
  hipLaunchKernelGGL(gx_kernel, dim3(MBLK), dim3(256), 0, stream,
                     x, W_in, b_in, b_ih, b_hh);
  hipLaunchKernelGGL(rec_kernel, dim3(NCL * 2), dim3(256), 0, stream, W_out, b_out, y);
}

// Round 9
// 2227.952 us; speedup vs baseline: 2.9543x; 2.9543x over previous
//
#include <hip/hip_runtime.h>
#include <hip/hip_fp16.h>

#define NT    365
#define NGRID 1000
#define NXI   20
#define HID   256
#define GATES 1024
#define MROWS 365000          // NT*NGRID
#define MBLK  5704            // ceil(MROWS/64)
#define MPAD  (MBLK * 64)
#define NCL   63              // clusters (16 pts each, last ragged)
#define CPTS  16
#define HX_TOT ((size_t)NT * NCL * 1024)   // u64 slots, deep buffer (188MB)
#define HX_ZERO ((size_t)NCL * 1024)       // t=0 region: zeros (h_0 = 0)

typedef _Float16 half8 __attribute__((ext_vector_type(8)));
typedef float floatx4 __attribute__((ext_vector_type(4)));
typedef unsigned long long u64;

#define SENT 0xFFFFFFFFFFFFFFFFull   // 4x fp16 -NaN: unreachable (|h|<=1)

// Module-scope globals (d_ws too small). Fully rewritten/reset every launch.
__device__ _Float16 g_gx[(size_t)MPAD * GATES];   // gx, block-local column layout
__device__ _Float16 g_wif[64 * 8 * 512];          // W_ih B-frags (global n-tiles)
__device__ _Float16 g_whf[2 * 32 * 8 * 64 * 8];   // W_hh B-frags, split by rec block
// h exchange, A-FRAGMENT ORDER, plane-split: slot[c][ks][lane] (c = u64 half
// of the half8). Poll loads are lane-contiguous -> perfectly coalesced.
// Sentinel protocol: value is its own ready-flag; deep t-indexed buffer.
__device__ u64 g_hx[HX_TOT];

__device__ __forceinline__ float fsig(float x) {
  return __fdividef(1.f, 1.f + __expf(-x));
}
__device__ __forceinline__ float ftanh(float x) {
  return 1.f - __fdividef(2.f, __expf(2.f * x) + 1.f);
}

// ---- init: zero y, zero g_hx[t=0], sentinel-fill the rest -----------------
__global__ __launch_bounds__(256) void init_kernel(float* __restrict__ y) {
  const size_t i = (size_t)blockIdx.x * 256 + threadIdx.x;
  const size_t j = i * 2;
  if (j < HX_TOT)     g_hx[j]     = (j < HX_ZERO)     ? 0ull : SENT;
  if (j + 1 < HX_TOT) g_hx[j + 1] = (j + 1 < HX_ZERO) ? 0ull : SENT;
  if (i < MROWS) y[i] = 0.f;
}

// ---- pack weights into MFMA B-fragment layouts ----------------------------
// B-frag 16x16x32: lane holds B[n=tile*16+(lane&15)][k=ks*32+(lane>>4)*8+j]
__global__ __launch_bounds__(256) void pack_wf_kernel(
    const float* __restrict__ W_ih, const float* __restrict__ W_hh) {
  const int gid = blockIdx.x * 256 + threadIdx.x;   // 0..65535
  const float* src;
  _Float16* dst;
  int n, k0, lane;
  if (gid < 32768) {                 // W_ih -> g_wif, global n-tile layout
    const int tile = gid >> 9;
    const int ks   = (gid >> 6) & 7;
    lane = gid & 63;
    n  = tile * 16 + (lane & 15);
    k0 = ks * 32 + (lane >> 4) * 8;
    src = W_ih + n * HID + k0;
    dst = g_wif + ((size_t)(tile * 8 + ks) * 64 + lane) * 8;
  } else {                           // W_hh -> g_whf, [b][ltile][ks] layout
    const int rem = gid - 32768;
    const int b2  = rem >> 14;       // owning rec block (dim half)
    const int lt  = (rem >> 9) & 31; // local tile = tau*8 + sub
    const int ks  = (rem >> 6) & 7;
    lane = rem & 63;
    const int nt = (lt >> 3) * 16 + b2 * 8 + (lt & 7);
    n  = nt * 16 + (lane & 15);
    k0 = ks * 32 + (lane >> 4) * 8;
    src = W_hh + n * HID + k0;
    dst = g_whf + ((size_t)((b2 * 32 + lt) * 8 + ks) * 64 + lane) * 8;
  }
  const float4 a = *(const float4*)(src);
  const float4 b = *(const float4*)(src + 4);
  half8 h;
  h[0] = (_Float16)a.x; h[1] = (_Float16)a.y; h[2] = (_Float16)a.z; h[3] = (_Float16)a.w;
  h[4] = (_Float16)b.x; h[5] = (_Float16)b.y; h[6] = (_Float16)b.z; h[7] = (_Float16)b.w;
  *(half8*)dst = h;
}

// ---- gx = relu(x@W_in.T+b_in) @ W_ih.T + (b_ih+b_hh), fused ---------------
// Output column layout per row: phi(g) = b*512 + tau*128 + (g&127).
__global__ __launch_bounds__(256, 2) void gx_kernel(
    const float* __restrict__ x, const float* __restrict__ W_in,
    const float* __restrict__ b_in, const float* __restrict__ b_ih,
    const float* __restrict__ b_hh) {
  __shared__ float s_x[64 * NXI];
  __shared__ _Float16 s_x0[64 * 264];
  __shared__ _Float16 s_out[64 * 264];

  const int tid  = threadIdx.x;
  const int lane = tid & 63;
  const int w    = tid >> 6;
  const int m0   = blockIdx.x * 64;

  #pragma unroll
  for (int i = 0; i < 5; ++i) {
    const int idx = i * 256 + tid;
    size_t g = (size_t)m0 * NXI + idx;
    const size_t gmax = (size_t)MROWS * NXI - 1;
    if (g > gmax) g = gmax;
    s_x[idx] = x[g];
  }
  float wv[NXI];
  #pragma unroll
  for (int k = 0; k < NXI; ++k) wv[k] = W_in[tid * NXI + k];
  const float bv = b_in[tid];
  __syncthreads();

  for (int r = 0; r < 64; ++r) {
    float acc = bv;
    #pragma unroll
    for (int qq = 0; qq < 5; ++qq) {
      const float4 xa = *(const float4*)&s_x[r * NXI + qq * 4];
      acc += xa.x * wv[qq * 4 + 0] + xa.y * wv[qq * 4 + 1] +
             xa.z * wv[qq * 4 + 2] + xa.w * wv[qq * 4 + 3];
    }
    s_x0[r * 264 + tid] = (_Float16)fmaxf(acc, 0.f);
  }
  __syncthreads();

  for (int ng = 0; ng < 4; ++ng) {    // 4 groups of 256 gates
    floatx4 acc[4][4];
    #pragma unroll
    for (int mi = 0; mi < 4; ++mi)
      #pragma unroll
      for (int ni = 0; ni < 4; ++ni) acc[mi][ni] = (floatx4){0.f, 0.f, 0.f, 0.f};

    #pragma unroll
    for (int ks = 0; ks < 8; ++ks) {
      half8 a[4], bfr[4];
      #pragma unroll
      for (int mi = 0; mi < 4; ++mi)
        a[mi] = *(const half8*)&s_x0[(mi * 16 + (lane & 15)) * 264 + ks * 32 + (lane >> 4) * 8];
      #pragma unroll
      for (int ni = 0; ni < 4; ++ni) {
        const int nt = ng * 16 + w * 4 + ni;
        bfr[ni] = *(const half8*)(g_wif + ((size_t)(nt * 8 + ks) * 64 + lane) * 8);
      }
      #pragma unroll
      for (int mi = 0; mi < 4; ++mi)
        #pragma unroll
        for (int ni = 0; ni < 4; ++ni)
          acc[mi][ni] = __builtin_amdgcn_mfma_f32_16x16x32_f16(a[mi], bfr[ni], acc[mi][ni], 0, 0, 0);
    }

    #pragma unroll
    for (int ni = 0; ni < 4; ++ni) {
      const int g = ng * 256 + (w * 4 + ni) * 16 + (lane & 15);
      const float bias = b_ih[g] + b_hh[g];
      const int colw = (w * 4 + ni) * 16 + (lane & 15);
      #pragma unroll
      for (int mi = 0; mi < 4; ++mi)
        #pragma unroll
        for (int r = 0; r < 4; ++r)
          s_out[(mi * 16 + (lane >> 4) * 4 + r) * 264 + colw] = (_Float16)(acc[mi][ni][r] + bias);
    }
    __syncthreads();

    #pragma unroll
    for (int i = 0; i < 8; ++i) {
      const int cid = i * 256 + tid;             // 2048 chunks of 8 halfs
      const int row = cid >> 5;
      const int c8  = (cid & 31) * 8;
      const half8 v = *(const half8*)&s_out[row * 264 + c8];
      const int phi = ((c8 >> 7) & 1) * 512 + ng * 128 + (c8 & 127);
      *(half8*)(g_gx + (size_t)(m0 + row) * GATES + phi) = v;
    }
    __syncthreads();
  }
}

// ---- recurrent: 63 clusters x 2 blocks; 256KB W_hh/block in registers ----
// Block b owns h dims [b*128,(b+1)*128) = ks slices b*4..b*4+3. Own half
// comes from LDS (s_hl); only the PEER's 4 ks slices are polled from the LLC
// (coalesced plane-split A-order). wf is indexed ONLY by compile-time
// constants: slots 0..3 = own ks (b*4+kk), slots 4..7 = peer ks. Runtime b
// lives in the LOAD ADDRESSES only — a runtime register-array index demotes
// the whole array to scratch (round 8: VGPR 196->104, FETCH +3.3GB).
__global__ __launch_bounds__(256, 1) void rec_kernel(
    const float* __restrict__ W_out, const float* __restrict__ b_out,
    float* __restrict__ y) {
  __shared__ float    s_g[16 * 516];   // 16 pts x 512 local gates (+4 pad)
  __shared__ _Float16 s_gx[16 * 520];  // padded rows: conflict-free 16B writes
  __shared__ u64      s_hl[512];       // own half, A-order: c*256 + ks_rel*64 + lane

  const int tid  = threadIdx.x;
  const int lane = tid & 63;
  const int w    = tid >> 6;
  const int c    = blockIdx.x >> 1;    // cluster
  const int b    = blockIdx.x & 1;     // dim-half owner

  const int ks_own0  = b * 4;          // our global ks slices
  const int ks_peer0 = 4 - b * 4;      // peer's global ks slices

  // one-time: 256KB W_hh slice -> registers, SLOT order (own 0..3, peer 4..7)
  half8 wf[8][8];
  #pragma unroll
  for (int i = 0; i < 8; ++i) {
    #pragma unroll
    for (int kk = 0; kk < 4; ++kk) {
      wf[i][kk] = *(const half8*)(g_whf +
          ((size_t)((b * 32 + w * 8 + i) * 8 + (ks_own0 + kk)) * 64 + lane) * 8);
      wf[i][4 + kk] = *(const half8*)(g_whf +
          ((size_t)((b * 32 + w * 8 + i) * 8 + (ks_peer0 + kk)) * 64 + lane) * 8);
    }
  }

  // cell ownership: pt = tid>>4, local dims q*8..q*8+8 (global b*128 + ...)
  const int pt = tid >> 4;
  const int q  = tid & 15;
  float cs[8];
  float wo[8];
  #pragma unroll
  for (int j = 0; j < 8; ++j) {
    cs[j] = 0.f;
    wo[j] = W_out[b * 128 + q * 8 + j];
  }
  const float bo = (b == 0) ? b_out[0] : 0.f;
  const int n_pt  = c * CPTS + pt;
  const int rn_pt = (n_pt < NGRID) ? n_pt : (NGRID - 1);

  // publish/LDS index pieces: local kb = q>>2 (rel ks), lane_a = pt+16*(q&3)
  const int pub_lane = pt + 16 * (q & 3);
  const int pub_ks_rel = q >> 2;

  // h_0 = 0 in own-half LDS
  for (int i = tid; i < 512; i += 256) s_hl[i] = 0ull;
  __syncthreads();

  for (int t = 0; t < NT; ++t) {
    // 1) gx prefetch (HBM, hidden behind everything): 64B per thread
    half8 gxr[4];
    {
      const _Float16* gsrc = g_gx + ((size_t)t * NGRID + rn_pt) * GATES + b * 512 + q * 32;
      #pragma unroll
      for (int k = 0; k < 4; ++k) gxr[k] = *(const half8*)(gsrc + k * 8);
    }

    // 2) issue peer-half poll loads (coalesced: 8B lane stride)
    const u64* hsrc = g_hx + ((size_t)t * NCL + c) * 1024;
    u64 pv[8];
    #pragma unroll
    for (int kk = 0; kk < 4; ++kk) {
      pv[2 * kk]     = __hip_atomic_load(hsrc +       (ks_peer0 + kk) * 64 + lane,
                                         __ATOMIC_RELAXED, __HIP_MEMORY_SCOPE_AGENT);
      pv[2 * kk + 1] = __hip_atomic_load(hsrc + 512 + (ks_peer0 + kk) * 64 + lane,
                                         __ATOMIC_RELAXED, __HIP_MEMORY_SCOPE_AGENT);
    }

    floatx4 acc[8];
    #pragma unroll
    for (int i = 0; i < 8; ++i) acc[i] = (floatx4){0.f, 0.f, 0.f, 0.f};

    // 3) own-half MFMAs from LDS while peer loads are in flight
    #pragma unroll
    for (int kk = 0; kk < 4; ++kk) {
      union { u64 u[2]; half8 h; } af;
      af.u[0] = s_hl[kk * 64 + lane];
      af.u[1] = s_hl[256 + kk * 64 + lane];
      #pragma unroll
      for (int i = 0; i < 8; ++i)
        acc[i] = __builtin_amdgcn_mfma_f32_16x16x32_f16(af.h, wf[i][kk], acc[i], 0, 0, 0);
    }

    // 4) peer-half: spin per slice (value is its own flag), then MFMA
    #pragma unroll
    for (int kk = 0; kk < 4; ++kk) {
      const u64* a0 = hsrc +       (ks_peer0 + kk) * 64 + lane;
      const u64* a1 = hsrc + 512 + (ks_peer0 + kk) * 64 + lane;
      int tries = 0;
      while (pv[2 * kk] == SENT && ++tries < (1 << 20))
        pv[2 * kk] = __hip_atomic_load(a0, __ATOMIC_RELAXED, __HIP_MEMORY_SCOPE_AGENT);
      tries = 0;
      while (pv[2 * kk + 1] == SENT && ++tries < (1 << 20))
        pv[2 * kk + 1] = __hip_atomic_load(a1, __ATOMIC_RELAXED, __HIP_MEMORY_SCOPE_AGENT);
      union { u64 u[2]; half8 h; } af;
      af.u[0] = pv[2 * kk];
      af.u[1] = pv[2 * kk + 1];
      #pragma unroll
      for (int i = 0; i < 8; ++i)
        acc[i] = __builtin_amdgcn_mfma_f32_16x16x32_f16(af.h, wf[i][4 + kk], acc[i], 0, 0, 0);
    }

    // 5) stage gate pre-acts + gx to LDS
    #pragma unroll
    for (int i = 0; i < 8; ++i) {
      const int col = (w * 8 + i) * 16 + (lane & 15);
      #pragma unroll
      for (int r = 0; r < 4; ++r)
        s_g[((lane >> 4) * 4 + r) * 516 + col] = acc[i][r];
    }
    {
      _Float16* d = &s_gx[pt * 520 + q * 32];
      #pragma unroll
      for (int k = 0; k < 4; ++k) *(half8*)(d + k * 8) = gxr[k];
    }
    __syncthreads(); // B1: s_g, s_gx ready; s_hl fully consumed

    // 6) cell update (8 dims); publish peer copy + own-half LDS ASAP
    {
      const float*    gp = &s_g[pt * 516 + q * 8];
      const _Float16* xp = &s_gx[pt * 520 + q * 8];
      union { u64 u[2]; _Float16 h[8]; } pub;
      float yp = 0.f;
      #pragma unroll
      for (int j = 0; j < 8; ++j) {
        const float gi = gp[j]       + (float)xp[j];
        const float gf = gp[128 + j] + (float)xp[128 + j];
        const float gg = gp[256 + j] + (float)xp[256 + j];
        const float go = gp[384 + j] + (float)xp[384 + j];
        const float i_ = fsig(gi);
        const float f_ = fsig(gf);
        const float g_ = ftanh(gg);
        const float o_ = fsig(go);
        cs[j] = f_ * cs[j] + i_ * g_;
        const float h = o_ * ftanh(cs[j]);
        pub.h[j] = (_Float16)h;
        yp += wo[j] * h;
      }
      if (t < NT - 1) {
        u64* dst = g_hx + ((size_t)(t + 1) * NCL + c) * 1024
                 + (ks_own0 + pub_ks_rel) * 64 + pub_lane;
        __hip_atomic_store(dst,       pub.u[0], __ATOMIC_RELAXED, __HIP_MEMORY_SCOPE_AGENT);
        __hip_atomic_store(dst + 512, pub.u[1], __ATOMIC_RELAXED, __HIP_MEMORY_SCOPE_AGENT);
      }
      s_hl[pub_ks_rel * 64 + pub_lane]       = pub.u[0];
      s_hl[256 + pub_ks_rel * 64 + pub_lane] = pub.u[1];
      yp += __shfl_xor(yp, 1);
      yp += __shfl_xor(yp, 2);
      yp += __shfl_xor(yp, 4);
      yp += __shfl_xor(yp, 8);
      if (q == 0 && n_pt < NGRID)
        atomicAdd(&y[(size_t)t * NGRID + n_pt], yp + bo);
    }
    __syncthreads(); // B2: s_hl(t+1) ready; s_g/s_gx reusable; stores drained
  }
}

extern "C" void kernel_launch(void* const* d_in, const int* in_sizes, int n_in,
                              void* d_out, int out_size, void* d_ws, size_t ws_size,
                              hipStream_t stream) {
  (void)in_sizes; (void)n_in; (void)out_size; (void)d_ws; (void)ws_size;
  const float* x     = (const float*)d_in[0];
  // d_in[1] = wt_ih (zeros in eval mode, unused)
  const float* W_in  = (const float*)d_in[2];
  const float* b_in  = (const float*)d_in[3];
  const float* W_ih  = (const float*)d_in[4];
  const float* W_hh  = (const float*)d_in[5];
  const float* b_ih  = (const float*)d_in[6];
  const float* b_hh  = (const float*)d_in[7];
  const float* W_out = (const float*)d_in[8];
  const float* b_out = (const float*)d_in[9];
  float* y           = (float*)d_out;

  const int init_blocks = (int)((HX_TOT / 2 + 255) / 256);
  hipLaunchKernelGGL(init_kernel, dim3(init_blocks), dim3(256), 0, stream, y);
  hipLaunchKernelGGL(pack_wf_kernel, dim3(256), dim3(256), 0, stream, W_ih, W_hh);
  hipLaunchKernelGGL(gx_kernel, dim3(MBLK), dim3(256), 0, stream,
                     x, W_in, b_in, b_ih, b_hh);
  hipLaunchKernelGGL(rec_kernel, dim3(NCL * 2), dim3(256), 0, stream, W_out, b_out, y);
}

// Round 10
// 1857.628 us; speedup vs baseline: 3.5432x; 1.1994x over previous
//
#include <hip/hip_runtime.h>
#include <hip/hip_fp16.h>

#define NT    365
#define NGRID 1000
#define NXI   20
#define HID   256
#define GATES 1024
#define MROWS 365000          // NT*NGRID
#define MBLK  5704            // ceil(MROWS/64)
#define MPAD  (MBLK * 64)
#define NCL   63              // clusters (16 pts each, last ragged)
#define CPTS  16
#define HX_TOT ((size_t)NT * NCL * 1024)   // u64 slots, deep buffer (188MB)
#define HX_ZERO ((size_t)NCL * 1024)       // t=0 region: zeros (h_0 = 0)

typedef _Float16 half8 __attribute__((ext_vector_type(8)));
typedef float floatx4 __attribute__((ext_vector_type(4)));
typedef unsigned long long u64;

#define SENT 0xFFFFFFFFFFFFFFFFull   // 4x fp16 -NaN: unreachable (|h|<=1)

// Module-scope globals (d_ws too small). Fully rewritten/reset every launch.
__device__ _Float16 g_gx[(size_t)MPAD * GATES];   // gx, block-local column layout
__device__ _Float16 g_wif[64 * 8 * 512];          // W_ih B-frags (global n-tiles)
__device__ _Float16 g_whf[2 * 32 * 8 * 64 * 8];   // W_hh B-frags, split by rec block
// h exchange, A-FRAGMENT ORDER, plane-split: chunk[(ks)*64 + lane] (+512 for
// the 2nd u64 of the half8). Coalesced polls AND coalesced publishes (each
// wave owns exactly one ks slice). Sentinel protocol; deep t-indexed buffer.
__device__ u64 g_hx[HX_TOT];

__device__ __forceinline__ float fsig(float x) {
  return __fdividef(1.f, 1.f + __expf(-x));
}
__device__ __forceinline__ float ftanh(float x) {
  return 1.f - __fdividef(2.f, __expf(2.f * x) + 1.f);
}

// ---- init: zero y, zero g_hx[t=0], sentinel-fill the rest -----------------
__global__ __launch_bounds__(256) void init_kernel(float* __restrict__ y) {
  const size_t i = (size_t)blockIdx.x * 256 + threadIdx.x;
  const size_t j = i * 2;
  if (j < HX_TOT)     g_hx[j]     = (j < HX_ZERO)     ? 0ull : SENT;
  if (j + 1 < HX_TOT) g_hx[j + 1] = (j + 1 < HX_ZERO) ? 0ull : SENT;
  if (i < MROWS) y[i] = 0.f;
}

// ---- pack weights into MFMA B-fragment layouts ----------------------------
// B-frag 16x16x32: lane holds B[n=tile*16+(lane&15)][k=ks*32+(lane>>4)*8+j]
__global__ __launch_bounds__(256) void pack_wf_kernel(
    const float* __restrict__ W_ih, const float* __restrict__ W_hh) {
  const int gid = blockIdx.x * 256 + threadIdx.x;   // 0..65535
  const float* src;
  _Float16* dst;
  int n, k0, lane;
  if (gid < 32768) {                 // W_ih -> g_wif, global n-tile layout
    const int tile = gid >> 9;
    const int ks   = (gid >> 6) & 7;
    lane = gid & 63;
    n  = tile * 16 + (lane & 15);
    k0 = ks * 32 + (lane >> 4) * 8;
    src = W_ih + n * HID + k0;
    dst = g_wif + ((size_t)(tile * 8 + ks) * 64 + lane) * 8;
  } else {                           // W_hh -> g_whf, [b][ltile][ks global]
    const int rem = gid - 32768;
    const int b2  = rem >> 14;       // owning rec block (dim half)
    const int lt  = (rem >> 9) & 31; // local tile = tau*8 + sub
    const int ks  = (rem >> 6) & 7;
    lane = rem & 63;
    const int nt = (lt >> 3) * 16 + b2 * 8 + (lt & 7);
    n  = nt * 16 + (lane & 15);
    k0 = ks * 32 + (lane >> 4) * 8;
    src = W_hh + n * HID + k0;
    dst = g_whf + ((size_t)((b2 * 32 + lt) * 8 + ks) * 64 + lane) * 8;
  }
  const float4 a = *(const float4*)(src);
  const float4 b = *(const float4*)(src + 4);
  half8 h;
  h[0] = (_Float16)a.x; h[1] = (_Float16)a.y; h[2] = (_Float16)a.z; h[3] = (_Float16)a.w;
  h[4] = (_Float16)b.x; h[5] = (_Float16)b.y; h[6] = (_Float16)b.z; h[7] = (_Float16)b.w;
  *(half8*)dst = h;
}

// ---- gx = relu(x@W_in.T+b_in) @ W_ih.T + (b_ih+b_hh), fused ---------------
// Output column layout per row: phi(g) = b*512 + tau*128 + (g&127).
__global__ __launch_bounds__(256, 2) void gx_kernel(
    const float* __restrict__ x, const float* __restrict__ W_in,
    const float* __restrict__ b_in, const float* __restrict__ b_ih,
    const float* __restrict__ b_hh) {
  __shared__ float s_x[64 * NXI];
  __shared__ _Float16 s_x0[64 * 264];
  __shared__ _Float16 s_out[64 * 264];

  const int tid  = threadIdx.x;
  const int lane = tid & 63;
  const int w    = tid >> 6;
  const int m0   = blockIdx.x * 64;

  #pragma unroll
  for (int i = 0; i < 5; ++i) {
    const int idx = i * 256 + tid;
    size_t g = (size_t)m0 * NXI + idx;
    const size_t gmax = (size_t)MROWS * NXI - 1;
    if (g > gmax) g = gmax;
    s_x[idx] = x[g];
  }
  float wv[NXI];
  #pragma unroll
  for (int k = 0; k < NXI; ++k) wv[k] = W_in[tid * NXI + k];
  const float bv = b_in[tid];
  __syncthreads();

  for (int r = 0; r < 64; ++r) {
    float acc = bv;
    #pragma unroll
    for (int qq = 0; qq < 5; ++qq) {
      const float4 xa = *(const float4*)&s_x[r * NXI + qq * 4];
      acc += xa.x * wv[qq * 4 + 0] + xa.y * wv[qq * 4 + 1] +
             xa.z * wv[qq * 4 + 2] + xa.w * wv[qq * 4 + 3];
    }
    s_x0[r * 264 + tid] = (_Float16)fmaxf(acc, 0.f);
  }
  __syncthreads();

  for (int ng = 0; ng < 4; ++ng) {    // 4 groups of 256 gates
    floatx4 acc[4][4];
    #pragma unroll
    for (int mi = 0; mi < 4; ++mi)
      #pragma unroll
      for (int ni = 0; ni < 4; ++ni) acc[mi][ni] = (floatx4){0.f, 0.f, 0.f, 0.f};

    #pragma unroll
    for (int ks = 0; ks < 8; ++ks) {
      half8 a[4], bfr[4];
      #pragma unroll
      for (int mi = 0; mi < 4; ++mi)
        a[mi] = *(const half8*)&s_x0[(mi * 16 + (lane & 15)) * 264 + ks * 32 + (lane >> 4) * 8];
      #pragma unroll
      for (int ni = 0; ni < 4; ++ni) {
        const int nt = ng * 16 + w * 4 + ni;
        bfr[ni] = *(const half8*)(g_wif + ((size_t)(nt * 8 + ks) * 64 + lane) * 8);
      }
      #pragma unroll
      for (int mi = 0; mi < 4; ++mi)
        #pragma unroll
        for (int ni = 0; ni < 4; ++ni)
          acc[mi][ni] = __builtin_amdgcn_mfma_f32_16x16x32_f16(a[mi], bfr[ni], acc[mi][ni], 0, 0, 0);
    }

    #pragma unroll
    for (int ni = 0; ni < 4; ++ni) {
      const int g = ng * 256 + (w * 4 + ni) * 16 + (lane & 15);
      const float bias = b_ih[g] + b_hh[g];
      const int colw = (w * 4 + ni) * 16 + (lane & 15);
      #pragma unroll
      for (int mi = 0; mi < 4; ++mi)
        #pragma unroll
        for (int r = 0; r < 4; ++r)
          s_out[(mi * 16 + (lane >> 4) * 4 + r) * 264 + colw] = (_Float16)(acc[mi][ni][r] + bias);
    }
    __syncthreads();

    #pragma unroll
    for (int i = 0; i < 8; ++i) {
      const int cid = i * 256 + tid;             // 2048 chunks of 8 halfs
      const int row = cid >> 5;
      const int c8  = (cid & 31) * 8;
      const half8 v = *(const half8*)&s_out[row * 264 + c8];
      const int phi = ((c8 >> 7) & 1) * 512 + ng * 128 + (c8 & 127);
      *(half8*)(g_gx + (size_t)(m0 + row) * GATES + phi) = v;
    }
    __syncthreads();
  }
}

// ---- recurrent: 63 clusters x 2 blocks; wave-autonomous gate slices -------
// Wave w computes ALL 4 gate types for its 32 dims (tiles off*8+2w+s), so the
// cell update is wave-local: NO barrier between GEMM and cell (lgkmcnt only).
// Lane (pt=l&15, jg=l>>4) owns dims 32w+jg*8..+8 of the block's 128.
// Peer h polled with a BATCHED spin (all pending chunks re-issued per
// iteration -> detection ~1 RTT; round 9's 8 sequential spins cost 8 RTTs).
// Publish: wave w owns ks slice b*4+w -> 2 coalesced 512B stores.
__global__ __launch_bounds__(256, 1) void rec_kernel(
    const float* __restrict__ W_out, const float* __restrict__ b_out,
    float* __restrict__ y) {
  __shared__ float s_g[4 * 16 * 132];  // per-wave gate regions (pad 132)
  __shared__ u64   s_h[2][1024];       // own-half h, A-order, dbl-buffered

  const int tid = threadIdx.x;
  const int l   = tid & 63;
  const int w   = tid >> 6;
  const int c   = blockIdx.x >> 1;     // cluster
  const int b   = blockIdx.x & 1;      // dim-half owner
  const int pt  = l & 15;
  const int jg  = l >> 4;

  // one-time: W_hh slice -> registers. slot = off*2+s (all reg indices are
  // compile-time constants; runtime w/b only in ADDRESSES — round 8 lesson).
  half8 wf[8][8];
  #pragma unroll
  for (int slot = 0; slot < 8; ++slot) {
    const int lt = (slot >> 1) * 8 + 2 * w + (slot & 1);
    #pragma unroll
    for (int kk = 0; kk < 4; ++kk) {
      wf[slot][kk] = *(const half8*)(g_whf +
          ((size_t)((b * 32 + lt) * 8 + (b * 4 + kk)) * 64 + l) * 8);
      wf[slot][4 + kk] = *(const half8*)(g_whf +
          ((size_t)((b * 32 + lt) * 8 + ((1 - b) * 4 + kk)) * 64 + l) * 8);
    }
  }

  float cs[8];
  float wo[8];
  #pragma unroll
  for (int j = 0; j < 8; ++j) {
    cs[j] = 0.f;
    wo[j] = W_out[b * 128 + 32 * w + jg * 8 + j];
  }
  const float bo_eff = (b == 0 && w == 0) ? b_out[0] : 0.f;
  const int n_pt  = c * CPTS + pt;
  const int rn_pt = (n_pt < NGRID) ? n_pt : (NGRID - 1);
  const int peer0 = (1 - b) * 4;       // peer's global ks base

  // zero s_h buffer 0 (h_0 = 0)
  for (int i = tid; i < 1024; i += 256) s_h[0][i] = 0ull;
  __syncthreads();

  for (int t = 0; t < NT; ++t) {
    const int cur = t & 1, nxt = cur ^ 1;

    // 1) gx loads straight into the consuming lane's registers
    half8 gxr[4];
    {
      const _Float16* gsrc = g_gx + ((size_t)t * NGRID + rn_pt) * GATES
                           + b * 512 + 32 * w + jg * 8;
      #pragma unroll
      for (int off = 0; off < 4; ++off)
        gxr[off] = *(const half8*)(gsrc + off * 128);
    }

    // 2) issue peer poll loads (coalesced: 8B lane stride per chunk-slice)
    const u64* hsrc = g_hx + ((size_t)t * NCL + c) * 1024;
    u64 pv[8];
    #pragma unroll
    for (int kk = 0; kk < 4; ++kk) {
      pv[2 * kk]     = __hip_atomic_load(hsrc +       (peer0 + kk) * 64 + l,
                                         __ATOMIC_RELAXED, __HIP_MEMORY_SCOPE_AGENT);
      pv[2 * kk + 1] = __hip_atomic_load(hsrc + 512 + (peer0 + kk) * 64 + l,
                                         __ATOMIC_RELAXED, __HIP_MEMORY_SCOPE_AGENT);
    }

    floatx4 acc[8];
    #pragma unroll
    for (int i = 0; i < 8; ++i) acc[i] = (floatx4){0.f, 0.f, 0.f, 0.f};

    // 3) own-half MFMAs from LDS while peer loads are in flight
    #pragma unroll
    for (int kk = 0; kk < 4; ++kk) {
      union { u64 u[2]; half8 h; } af;
      af.u[0] = s_h[cur][kk * 64 + l];
      af.u[1] = s_h[cur][512 + kk * 64 + l];
      #pragma unroll
      for (int i = 0; i < 8; ++i)
        acc[i] = __builtin_amdgcn_mfma_f32_16x16x32_f16(af.h, wf[i][kk], acc[i], 0, 0, 0);
    }

    // 4) BATCHED spin: re-issue all pending chunks each iteration (~1 RTT)
    {
      bool pending = false;
      #pragma unroll
      for (int k = 0; k < 8; ++k) pending |= (pv[k] == SENT);
      int tries = 0;
      while (pending && ++tries < (1 << 18)) {
        pending = false;
        #pragma unroll
        for (int kk = 0; kk < 4; ++kk) {
          if (pv[2 * kk] == SENT)
            pv[2 * kk] = __hip_atomic_load(hsrc + (peer0 + kk) * 64 + l,
                                           __ATOMIC_RELAXED, __HIP_MEMORY_SCOPE_AGENT);
          if (pv[2 * kk + 1] == SENT)
            pv[2 * kk + 1] = __hip_atomic_load(hsrc + 512 + (peer0 + kk) * 64 + l,
                                               __ATOMIC_RELAXED, __HIP_MEMORY_SCOPE_AGENT);
        }
        #pragma unroll
        for (int k = 0; k < 8; ++k) pending |= (pv[k] == SENT);
      }
    }

    // 5) peer-half MFMAs
    #pragma unroll
    for (int kk = 0; kk < 4; ++kk) {
      union { u64 u[2]; half8 h; } af;
      af.u[0] = pv[2 * kk];
      af.u[1] = pv[2 * kk + 1];
      #pragma unroll
      for (int i = 0; i < 8; ++i)
        acc[i] = __builtin_amdgcn_mfma_f32_16x16x32_f16(af.h, wf[i][4 + kk], acc[i], 0, 0, 0);
    }

    // 6) scatter acc -> wave-local s_g region (no barrier: same-wave reuse)
    #pragma unroll
    for (int slot = 0; slot < 8; ++slot) {
      const int colw = (slot >> 1) * 32 + (slot & 1) * 16 + pt; // pt = lane&15
      #pragma unroll
      for (int r = 0; r < 4; ++r)
        s_g[w * 2112 + (jg * 4 + r) * 132 + colw] = acc[slot][r];
    }

    // 7) cell update for this lane's 8 dims (wave-local gates; lgkm only)
    {
      const float* gp = &s_g[w * 2112 + pt * 132 + jg * 8];
      union { u64 u[2]; _Float16 h[8]; } pub;
      float yp = 0.f;
      #pragma unroll
      for (int j = 0; j < 8; ++j) {
        const float gi = gp[j]      + (float)gxr[0][j];
        const float gf = gp[32 + j] + (float)gxr[1][j];
        const float gg = gp[64 + j] + (float)gxr[2][j];
        const float go = gp[96 + j] + (float)gxr[3][j];
        const float i_ = fsig(gi);
        const float f_ = fsig(gf);
        const float g_ = ftanh(gg);
        const float o_ = fsig(go);
        cs[j] = f_ * cs[j] + i_ * g_;
        const float h = o_ * ftanh(cs[j]);
        pub.h[j] = (_Float16)h;
        yp += wo[j] * h;
      }
      // 8) publish wave's ks slice (2 coalesced 512B stores) + own-half LDS
      if (t < NT - 1) {
        u64* dst = g_hx + ((size_t)(t + 1) * NCL + c) * 1024 + (b * 4 + w) * 64 + l;
        __hip_atomic_store(dst,       pub.u[0], __ATOMIC_RELAXED, __HIP_MEMORY_SCOPE_AGENT);
        __hip_atomic_store(dst + 512, pub.u[1], __ATOMIC_RELAXED, __HIP_MEMORY_SCOPE_AGENT);
      }
      s_h[nxt][w * 64 + l]       = pub.u[0];
      s_h[nxt][512 + w * 64 + l] = pub.u[1];
      // 9) y: reduce partial over the 4 jg-lanes of this pt, then atomicAdd
      yp += __shfl_xor(yp, 16);
      yp += __shfl_xor(yp, 32);
      if (jg == 0 && n_pt < NGRID)
        atomicAdd(&y[(size_t)t * NGRID + n_pt], yp + bo_eff);
    }
    __syncthreads(); // single barrier: s_h(t+1) complete across waves
  }
}

extern "C" void kernel_launch(void* const* d_in, const int* in_sizes, int n_in,
                              void* d_out, int out_size, void* d_ws, size_t ws_size,
                              hipStream_t stream) {
  (void)in_sizes; (void)n_in; (void)out_size; (void)d_ws; (void)ws_size;
  const float* x     = (const float*)d_in[0];
  // d_in[1] = wt_ih (zeros in eval mode, unused)
  const float* W_in  = (const float*)d_in[2];
  const float* b_in  = (const float*)d_in[3];
  const float* W_ih  = (const float*)d_in[4];
  const float* W_hh  = (const float*)d_in[5];
  const float* b_ih  = (const float*)d_in[6];
  const float* b_hh  = (const float*)d_in[7];
  const float* W_out = (const float*)d_in[8];
  const float* b_out = (const float*)d_in[9];
  float* y           = (float*)d_out;

  const int init_blocks = (int)((HX_TOT / 2 + 255) / 256);
  hipLaunchKernelGGL(init_kernel, dim3(init_blocks), dim3(256), 0, stream, y);
  hipLaunchKernelGGL(pack_wf_kernel, dim3(256), dim3(256), 0, stream, W_ih, W_hh);
  hipLaunchKernelGGL(gx_kernel, dim3(MBLK), dim3(256), 0, stream,
                     x, W_in, b_in, b_ih, b_hh);
  hipLaunchKernelGGL(rec_kernel, dim3(NCL * 2), dim3(256), 0, stream, W_out, b_out, y);
}